// Round 12
// baseline (311.655 us; speedup 1.0000x reference)
//
#include <hip/hip_runtime.h>

#define DIM_D 128
#define DIM_2D 256
#define DIM_H 128
#define DIM_O 64

#define BK_SHIFT 7
#define BK_SIZE  128
#define CHUNK    8192

struct EdgeSW { int s; float w; };   // 8B packed

typedef __attribute__((ext_vector_type(8))) short short8v;  // 8 bf16 (4 VGPRs)
typedef __attribute__((ext_vector_type(4))) float f32x4;    // 4 fp32 acc
typedef __attribute__((ext_vector_type(2))) float f32x2;    // packed pair (v_pk_fma_f32)

__device__ __forceinline__ EdgeSW ld_edge_nt(const EdgeSW* p)
{
    unsigned long long v =
        __builtin_nontemporal_load(reinterpret_cast<const unsigned long long*>(p));
    EdgeSW e;
    e.s = (int)(unsigned)(v & 0xFFFFFFFFull);
    union { unsigned u; float f; } w; w.u = (unsigned)(v >> 32); e.w = w.f;
    return e;
}

__device__ __forceinline__ unsigned short f2bf_rne(float f)
{
    union { float f; unsigned u; } v; v.f = f;
    unsigned u = v.u + 0x7FFFu + ((v.u >> 16) & 1u);
    return (unsigned short)(u >> 16);
}

__device__ __forceinline__ float bf2f(unsigned short h)
{
    union { unsigned u; float f; } v; v.u = ((unsigned)h) << 16;
    return v.f;
}

// ---------------------------------------------------------------------------
// prep (weight images + emb bf16 hi/lo tables) fused with bucket histogram.
// ---------------------------------------------------------------------------
__device__ __forceinline__ void split_bf(float x, unsigned short& hi, unsigned short& lo)
{
    union { float f; unsigned u; } v; v.f = x;
    hi = (unsigned short)(v.u >> 16);
    union { unsigned u; float f; } hv; hv.u = v.u & 0xFFFF0000u;
    union { float f; unsigned u; } rv; rv.f = x - hv.f;
    lo = (unsigned short)(rv.u >> 16);
}

__global__ __launch_bounds__(256) void prep_hist_k(
    const int* __restrict__ cp_dst, int* __restrict__ bcnt_p,
    const int* __restrict__ pc_dst, int* __restrict__ bcnt_c,
    int E, int CB, int nbk_p, int nbk_c,
    const float* __restrict__ W1p, const float* __restrict__ W2p,
    const float* __restrict__ W1c, const float* __restrict__ W2c,
    char* __restrict__ w1p_img, char* __restrict__ w2p_img,
    char* __restrict__ w1c_img, char* __restrict__ w2c_img,
    const float* __restrict__ pe, const float* __restrict__ ce,
    unsigned short* __restrict__ pe16, unsigned short* __restrict__ ce16,
    unsigned short* __restrict__ pe_lo, unsigned short* __restrict__ ce_lo,
    int np8, int nc8)
{
    __shared__ int lh[1024];
    int blk = blockIdx.x;
    const int t = threadIdx.x;

    if (blk < 2 * CB) {
        int b = blk;
        const int* dst; int* bcnt; int nbk;
        if (b < CB) { dst = cp_dst; bcnt = bcnt_p; nbk = nbk_p; }
        else        { dst = pc_dst; bcnt = bcnt_c; nbk = nbk_c; b -= CB; }
        const int e0 = b * CHUNK;
        const int e1 = min(e0 + CHUNK, E);
        if (e0 >= E) return;
        for (int i = t; i < nbk; i += 256) lh[i] = 0;
        __syncthreads();
        for (int i = e0 + t; i < e1; i += 256)
            atomicAdd(&lh[dst[i] >> BK_SHIFT], 1);
        __syncthreads();
        for (int i = t; i < nbk; i += 256) {
            int c = lh[i];
            if (c > 0) atomicAdd(&bcnt[i], c);
        }
        return;
    }

    int n = (blk - 2 * CB) * 256 + t;
    if (n < 40960) {
        int p = n;
        const float* W; char* img; int isW1; int lp;
        if (p < 16384)      { W = W1p; img = w1p_img; isW1 = 1; lp = p; }
        else if (p < 32768) { W = W1c; img = w1c_img; isW1 = 1; lp = p - 16384; }
        else if (p < 36864) { W = W2p; img = w2p_img; isW1 = 0; lp = p - 32768; }
        else                { W = W2c; img = w2c_img; isW1 = 0; lp = p - 36864; }
        int row, q, ncols;
        if (isW1) { row = lp >> 7; q = lp & 127; ncols = 256; }
        else      { row = lp >> 6; q = lp & 63;  ncols = 128; }
        int kc  = q >> 5;
        int cin = (q & 31) * 2;
        float a = W[(size_t)row * ncols + 2 * q];
        float b = W[(size_t)row * ncols + 2 * q + 1];
        unsigned short ah, al, bh, bl;
        split_bf(a, ah, al); split_bf(b, bh, bl);
        int half_sz = isW1 ? 16384 : 8192;
        size_t off = (size_t)kc * 2 * half_sz + (size_t)row * 128
                   + ((2 * cin) ^ ((row & 7) << 4));
        *reinterpret_cast<unsigned*>(img + off)           = (unsigned)ah | ((unsigned)bh << 16);
        *reinterpret_cast<unsigned*>(img + off + half_sz) = (unsigned)al | ((unsigned)bl << 16);
        return;
    }
    int i = n - 40960;
    const float* src; unsigned short* dst; unsigned short* dlo; int g;
    if (i < np8)            { src = pe; dst = pe16; dlo = pe_lo; g = i; }
    else if (i < np8 + nc8) { src = ce; dst = ce16; dlo = ce_lo; g = i - np8; }
    else return;
    float4 a = *reinterpret_cast<const float4*>(src + (size_t)g * 8);
    float4 b = *reinterpret_cast<const float4*>(src + (size_t)g * 8 + 4);
    unsigned short h[8], l[8];
    float x[8] = {a.x, a.y, a.z, a.w, b.x, b.y, b.z, b.w};
    #pragma unroll
    for (int j = 0; j < 8; ++j) {
        h[j] = f2bf_rne(x[j]);
        l[j] = f2bf_rne(x[j] - bf2f(h[j]));
    }
    uint4 o, ol;
    o.x  = (unsigned)h[0] | ((unsigned)h[1] << 16);
    o.y  = (unsigned)h[2] | ((unsigned)h[3] << 16);
    o.z  = (unsigned)h[4] | ((unsigned)h[5] << 16);
    o.w  = (unsigned)h[6] | ((unsigned)h[7] << 16);
    ol.x = (unsigned)l[0] | ((unsigned)l[1] << 16);
    ol.y = (unsigned)l[2] | ((unsigned)l[3] << 16);
    ol.z = (unsigned)l[4] | ((unsigned)l[5] << 16);
    ol.w = (unsigned)l[6] | ((unsigned)l[7] << 16);
    *reinterpret_cast<uint4*>(dst + (size_t)g * 8) = o;
    if (dlo) *reinterpret_cast<uint4*>(dlo + (size_t)g * 8) = ol;
}

// ---------------------------------------------------------------------------
// Exclusive prefix over bucket counts; seeds bstart (with sentinel) and bcur.
// ---------------------------------------------------------------------------
__global__ __launch_bounds__(256) void scan_buckets(
    const int* __restrict__ bcnt_p, int* __restrict__ bstart_p,
    int* __restrict__ bcur_p, int nbk_p,
    const int* __restrict__ bcnt_c, int* __restrict__ bstart_c,
    int* __restrict__ bcur_c, int nbk_c)
{
    const int* bcnt; int* bstart; int* bcur; int nbk;
    if (blockIdx.x == 0) { bcnt = bcnt_p; bstart = bstart_p; bcur = bcur_p; nbk = nbk_p; }
    else                 { bcnt = bcnt_c; bstart = bstart_c; bcur = bcur_c; nbk = nbk_c; }
    int t = threadIdx.x;
    int base = t * 4;
    int v[4]; int s = 0;
    #pragma unroll
    for (int k = 0; k < 4; ++k) { int i = base + k; v[k] = (i < nbk) ? bcnt[i] : 0; s += v[k]; }
    __shared__ int sh[256];
    sh[t] = s; __syncthreads();
    for (int off = 1; off < 256; off <<= 1) {
        int x = 0;
        if (t >= off) x = sh[t - off];
        __syncthreads();
        if (t >= off) sh[t] += x;
        __syncthreads();
    }
    int run = (t > 0 ? sh[t - 1] : 0);
    #pragma unroll
    for (int k = 0; k < 4; ++k) {
        int i = base + k;
        if (i < nbk) {
            bstart[i] = run;
            bcur[i]   = run;
            run += v[k];
            if (i == nbk - 1) bstart[nbk] = run;
        }
    }
}

// ---------------------------------------------------------------------------
// Pass A: bin edges by dst>>7 with block-aggregated cursor updates.
// ---------------------------------------------------------------------------
__global__ __launch_bounds__(256) void bin_both(
    const int* __restrict__ cp_edges, int* __restrict__ bcur_p,
    uint2* __restrict__ bin_cp,
    const int* __restrict__ pc_edges, int* __restrict__ bcur_c,
    uint2* __restrict__ bin_pc,
    const float* __restrict__ ew, int E, int CB, int NBKp, int NBKc)
{
    __shared__ int lh[1024];
    int b = blockIdx.x;
    const int* src; const int* dst; int* bcur; uint2* bin; int nbk;
    if (b < CB) { src = cp_edges; dst = cp_edges + E; bcur = bcur_p; bin = bin_cp; nbk = NBKp; }
    else        { src = pc_edges; dst = pc_edges + E; bcur = bcur_c; bin = bin_pc; nbk = NBKc; b -= CB; }
    const int t  = threadIdx.x;
    const int e0 = b * CHUNK;
    const int e1 = min(e0 + CHUNK, E);
    if (e0 >= E) return;

    for (int i = t; i < nbk; i += 256) lh[i] = 0;
    __syncthreads();
    for (int i = e0 + t; i < e1; i += 256)
        atomicAdd(&lh[dst[i] >> BK_SHIFT], 1);
    __syncthreads();

    for (int i = t; i < nbk; i += 256) {
        int c = lh[i];
        if (c > 0) lh[i] = atomicAdd(&bcur[i], c);
    }
    __syncthreads();

    for (int i = e0 + t; i < e1; i += 256) {
        int d = dst[i];
        int pos = atomicAdd(&lh[d >> BK_SHIFT], 1);
        uint2 r;
        r.x = (unsigned)src[i] | ((unsigned)(d & (BK_SIZE - 1)) << 25);
        union { float f; unsigned u; } w; w.f = ew[i];
        r.y = w.u;
        bin[pos] = r;
    }
}

// ---------------------------------------------------------------------------
// Pass B: one block per bucket; local per-node starts; L2-local scatter.
// ---------------------------------------------------------------------------
__global__ __launch_bounds__(256) void place2_both(
    const uint2* __restrict__ bin_cp, const int* __restrict__ bstart_p,
    int* __restrict__ starts_p, EdgeSW* __restrict__ csr_cp, int NP, int NBKp,
    const uint2* __restrict__ bin_pc, const int* __restrict__ bstart_c,
    int* __restrict__ starts_c, EdgeSW* __restrict__ csr_pc, int NC)
{
    int b = blockIdx.x;
    const uint2* bin; const int* bstart; int* starts; EdgeSW* csr; int N;
    if (b < NBKp) { bin = bin_cp; bstart = bstart_p; starts = starts_p; csr = csr_cp; N = NP; }
    else          { bin = bin_pc; bstart = bstart_c; starts = starts_c; csr = csr_pc; N = NC; b -= NBKp; }
    int d0 = b << BK_SHIFT;
    if (d0 >= N) return;
    int nd = min(BK_SIZE, N - d0);

    __shared__ int lcnt[BK_SIZE];
    __shared__ int lpre[BK_SIZE];
    __shared__ int lcur[BK_SIZE];
    int t = threadIdx.x;
    if (t < BK_SIZE) lcnt[t] = 0;
    __syncthreads();

    int rs = bstart[b], re = bstart[b + 1];
    for (int i = rs + t; i < re; i += 256)
        atomicAdd(&lcnt[bin[i].x >> 25], 1);
    __syncthreads();

    if (t < BK_SIZE) lpre[t] = lcnt[t];
    __syncthreads();
    #pragma unroll
    for (int off = 1; off < BK_SIZE; off <<= 1) {
        int x = 0;
        if (t < BK_SIZE && t >= off) x = lpre[t - off];
        __syncthreads();
        if (t < BK_SIZE && t >= off) lpre[t] += x;
        __syncthreads();
    }
    if (t < BK_SIZE) {
        int excl = rs + lpre[t] - lcnt[t];
        lcur[t] = excl;
        if (t < nd) starts[d0 + t] = excl;
    }
    if (t == 0 && d0 + BK_SIZE >= N) starts[N] = re;
    __syncthreads();

    for (int i = rs + t; i < re; i += 256) {
        uint2 r = bin[i];
        int dlo = (int)(r.x >> 25);
        int pos = atomicAdd(&lcur[dlo], 1);
        EdgeSW e;
        e.s = (int)(r.x & 0x1FFFFFFu);
        union { unsigned u; float f; } w; w.u = r.y; e.w = w.f;
        csr[pos] = e;
    }
}

// ---------------------------------------------------------------------------
// Gather: wave per node; 16 lanes/row (uint4 = 8 bf16), 4 edges across wave
// quarters. Packed f32x2 accumulate; 32-bit indexed emb loads. Output:
// swizzled bf16 hi/lo msg planes (the MLP's XS image).
// ---------------------------------------------------------------------------
__device__ __forceinline__ void fma8p(f32x2* acc, uint4 v, float w)
{
    union { unsigned u; float f; } a, b;
    f32x2 p;
    a.u = v.x << 16; b.u = v.x & 0xFFFF0000u; p[0] = a.f; p[1] = b.f; acc[0] += p * w;
    a.u = v.y << 16; b.u = v.y & 0xFFFF0000u; p[0] = a.f; p[1] = b.f; acc[1] += p * w;
    a.u = v.z << 16; b.u = v.z & 0xFFFF0000u; p[0] = a.f; p[1] = b.f; acc[2] += p * w;
    a.u = v.w << 16; b.u = v.w & 0xFFFF0000u; p[0] = a.f; p[1] = b.f; acc[3] += p * w;
}

__global__ __launch_bounds__(256) void gather_both(
    const EdgeSW* __restrict__ csr_cp, const int* __restrict__ starts_p,
    const unsigned short* __restrict__ c_emb16,
    char* __restrict__ msg_hi_p, char* __restrict__ msg_lo_p, int NP,
    const EdgeSW* __restrict__ csr_pc, const int* __restrict__ starts_c,
    const unsigned short* __restrict__ p_emb16,
    char* __restrict__ msg_hi_c, char* __restrict__ msg_lo_c, int NC)
{
    int wv = (blockIdx.x * 256 + threadIdx.x) >> 6;
    int lane = threadIdx.x & 63;
    const EdgeSW* csr; const int* starts; const unsigned short* emb;
    char* mh; char* ml; int n;
    if (wv < NP)           { csr = csr_cp; starts = starts_p; emb = c_emb16;
                             mh = msg_hi_p; ml = msg_lo_p; n = wv; }
    else if (wv < NP + NC) { csr = csr_pc; starts = starts_c; emb = p_emb16;
                             mh = msg_hi_c; ml = msg_lo_c; n = wv - NP; }
    else return;

    const int sub = lane >> 4;          // edge slot within quad
    const int l15 = lane & 15;
    const int cb  = l15 * 8;            // col base (8 bf16 = 16B)
    const uint4* embq = reinterpret_cast<const uint4*>(emb);

    auto eidx = [&](int s) -> unsigned {
        return ((((unsigned)s) & 0xFFFFFFu) << 4) | (unsigned)l15;
    };

    int s0 = starts[n], s1 = starts[n + 1];
    f32x2 a2[4];
    a2[0] = 0.f; a2[1] = 0.f; a2[2] = 0.f; a2[3] = 0.f;
    float degw = 0.f;
    int i = s0;
    for (; i + 16 <= s1; i += 16) {
        EdgeSW e0 = ld_edge_nt(csr + i + sub);
        EdgeSW e1 = ld_edge_nt(csr + i + 4 + sub);
        EdgeSW e2 = ld_edge_nt(csr + i + 8 + sub);
        EdgeSW e3 = ld_edge_nt(csr + i + 12 + sub);
        uint4 v0 = embq[eidx(e0.s)];
        uint4 v1 = embq[eidx(e1.s)];
        uint4 v2 = embq[eidx(e2.s)];
        uint4 v3 = embq[eidx(e3.s)];
        fma8p(a2, v0, e0.w); fma8p(a2, v1, e1.w);
        fma8p(a2, v2, e2.w); fma8p(a2, v3, e3.w);
        degw += e0.w + e1.w + e2.w + e3.w;
    }
    if (i + 8 <= s1) {
        EdgeSW e0 = ld_edge_nt(csr + i + sub);
        EdgeSW e1 = ld_edge_nt(csr + i + 4 + sub);
        uint4 v0 = embq[eidx(e0.s)];
        uint4 v1 = embq[eidx(e1.s)];
        fma8p(a2, v0, e0.w); fma8p(a2, v1, e1.w);
        degw += e0.w + e1.w;
        i += 8;
    }
    for (; i < s1; i += 4) {
        int idx = i + sub;
        if (idx < s1) {
            EdgeSW e0 = ld_edge_nt(csr + idx);
            uint4 v0 = embq[eidx(e0.s)];
            fma8p(a2, v0, e0.w);
            degw += e0.w;
        }
    }
    degw += __shfl_xor(degw, 16);
    degw += __shfl_xor(degw, 32);
    #pragma unroll
    for (int j = 0; j < 4; ++j) {
        a2[j][0] += __shfl_xor(a2[j][0], 16);
        a2[j][0] += __shfl_xor(a2[j][0], 32);
        a2[j][1] += __shfl_xor(a2[j][1], 16);
        a2[j][1] += __shfl_xor(a2[j][1], 32);
    }
    if (lane < 16) {
        float inv = 1.0f / (degw + 1e-8f);
        unsigned h[8], l[8];
        #pragma unroll
        for (int j = 0; j < 8; ++j) {
            float x = a2[j >> 1][j & 1] * inv;
            unsigned short hh = f2bf_rne(x);
            unsigned short ll = f2bf_rne(x - bf2f(hh));
            h[j] = hh; l[j] = ll;
        }
        uint4 hv, lv;
        hv.x = h[0] | (h[1] << 16); hv.y = h[2] | (h[3] << 16);
        hv.z = h[4] | (h[5] << 16); hv.w = h[6] | (h[7] << 16);
        lv.x = l[0] | (l[1] << 16); lv.y = l[2] | (l[3] << 16);
        lv.z = l[4] | (l[5] << 16); lv.w = l[6] | (l[7] << 16);
        size_t base = (size_t)n * 256 + ((cb * 2) ^ ((n & 7) << 4));
        *reinterpret_cast<uint4*>(mh + base) = hv;
        *reinterpret_cast<uint4*>(ml + base) = lv;
    }
}

// ---------------------------------------------------------------------------
// Fused MLP via bf16x3 MFMA. All staging is pure uint4 copies when the
// pre-split emb lo-table is available (hi from emb16, lo from emb_lo16,
// swizzle folded into the LDS write address); fp32-split fallback otherwise.
// ---------------------------------------------------------------------------
#define XS_HI  0
#define XS_LO  8192
#define W1S    16384     // 32 KB: hi 16KB | lo 16KB
#define YS_HI  0
#define YS_LO  16384
#define W2S    32768     // 16 KB: hi 8KB | lo 8KB
#define SMEM_BYTES 49152

__device__ __forceinline__ void stage_pair(char* hi_base, char* lo_base,
                                           int row, int rowbytes, int posB, float4 v)
{
    int byte = row * rowbytes + (posB ^ ((row & 7) << 4));
    unsigned short h0, h1, h2, h3, l0, l1, l2, l3;
    split_bf(v.x, h0, l0); split_bf(v.y, h1, l1);
    split_bf(v.z, h2, l2); split_bf(v.w, h3, l3);
    uint2 hp, lp;
    hp.x = (unsigned)h0 | ((unsigned)h1 << 16);
    hp.y = (unsigned)h2 | ((unsigned)h3 << 16);
    lp.x = (unsigned)l0 | ((unsigned)l1 << 16);
    lp.y = (unsigned)l2 | ((unsigned)l3 << 16);
    *reinterpret_cast<uint2*>(hi_base + byte) = hp;
    *reinterpret_cast<uint2*>(lo_base + byte) = lp;
}

__device__ __forceinline__ short8v ld_frag(const char* base, int row, int rowbytes, int posB)
{
    int byte = row * rowbytes + (posB ^ ((row & 7) << 4));
    return *reinterpret_cast<const short8v*>(base + byte);
}

__device__ __forceinline__ void mlp_body(int blk,
    const float* __restrict__ emb,
    const unsigned short* __restrict__ emb16,
    const unsigned short* __restrict__ emb_lo,
    const char* __restrict__ msg_hi, const char* __restrict__ msg_lo,
    const char* __restrict__ w1img, const char* __restrict__ w2img,
    const float* __restrict__ b1, const float* __restrict__ g1,
    const float* __restrict__ be1,
    const float* __restrict__ b2, const float* __restrict__ g2,
    const float* __restrict__ be2,
    float* __restrict__ out, int N)
{
    __shared__ uint4 smem4[SMEM_BYTES / 16];
    char* smem = reinterpret_cast<char*>(smem4);

    const int t    = threadIdx.x;
    const int lane = t & 63;
    const int wv   = t >> 6;
    const int l15  = lane & 15;
    const int g    = lane >> 4;
    const int r0   = blk * 64;

    f32x4 acc[8];
    #pragma unroll
    for (int nt = 0; nt < 8; ++nt)
        #pragma unroll
        for (int r = 0; r < 4; ++r) acc[nt][r] = 0.f;

    for (int kc = 0; kc < 4; ++kc) {
        if (kc < 2) {
            if (emb_lo) {
                // pure-copy staging from pre-split linear tables
                int base_us = kc * 64;
                #pragma unroll
                for (int q = 0; q < 2; ++q) {
                    int idx = t + q * 256;
                    int row = idx >> 3;
                    int j   = idx & 7;
                    int node = r0 + row;
                    uint4 vh = make_uint4(0, 0, 0, 0), vl = make_uint4(0, 0, 0, 0);
                    if (node < N) {
                        size_t o = (size_t)node * DIM_D + base_us + j * 8;
                        vh = *reinterpret_cast<const uint4*>(emb16 + o);
                        vl = *reinterpret_cast<const uint4*>(emb_lo + o);
                    }
                    int ldsoff = row * 128 + ((j * 16) ^ ((row & 7) << 4));
                    *reinterpret_cast<uint4*>(smem + XS_HI + ldsoff) = vh;
                    *reinterpret_cast<uint4*>(smem + XS_LO + ldsoff) = vl;
                }
            } else {
                #pragma unroll
                for (int i = 0; i < 4; ++i) {
                    int lin = t + i * 256;
                    int row = lin >> 4;
                    int c4  = (lin & 15) << 2;
                    int node = r0 + row;
                    float4 v = make_float4(0.f, 0.f, 0.f, 0.f);
                    if (node < N)
                        v = *reinterpret_cast<const float4*>(emb + (size_t)node * DIM_D + kc * 64 + c4);
                    stage_pair(smem + XS_HI, smem + XS_LO, row, 128, c4 * 2, v);
                }
            }
        } else {
            int base = (kc - 2) * 128;
            #pragma unroll
            for (int q = 0; q < 2; ++q) {
                int idx = t + q * 256;
                int row = idx >> 3;
                int j   = idx & 7;
                int node = r0 + row;
                uint4 vh = make_uint4(0, 0, 0, 0), vl = make_uint4(0, 0, 0, 0);
                if (node < N) {
                    vh = *reinterpret_cast<const uint4*>(msg_hi + (size_t)node * 256 + base + j * 16);
                    vl = *reinterpret_cast<const uint4*>(msg_lo + (size_t)node * 256 + base + j * 16);
                }
                *reinterpret_cast<uint4*>(smem + XS_HI + row * 128 + j * 16) = vh;
                *reinterpret_cast<uint4*>(smem + XS_LO + row * 128 + j * 16) = vl;
            }
        }
        {
            const char* src = w1img + (size_t)kc * 32768;
            #pragma unroll
            for (int i = 0; i < 8; ++i) {
                int b = (t + i * 256) * 16;
                *reinterpret_cast<uint4*>(smem + W1S + b) =
                    *reinterpret_cast<const uint4*>(src + b);
            }
        }
        __syncthreads();
        #pragma unroll
        for (int ks = 0; ks < 2; ++ks) {
            int pos = ks * 64 + g * 16;
            short8v a_hi = ld_frag(smem + XS_HI, wv * 16 + l15, 128, pos);
            short8v a_lo = ld_frag(smem + XS_LO, wv * 16 + l15, 128, pos);
            #pragma unroll
            for (int nt = 0; nt < 8; ++nt) {
                short8v b_hi = ld_frag(smem + W1S,         nt * 16 + l15, 128, pos);
                short8v b_lo = ld_frag(smem + W1S + 16384, nt * 16 + l15, 128, pos);
                acc[nt] = __builtin_amdgcn_mfma_f32_16x16x32_bf16(a_hi, b_hi, acc[nt], 0, 0, 0);
                acc[nt] = __builtin_amdgcn_mfma_f32_16x16x32_bf16(a_hi, b_lo, acc[nt], 0, 0, 0);
                acc[nt] = __builtin_amdgcn_mfma_f32_16x16x32_bf16(a_lo, b_hi, acc[nt], 0, 0, 0);
            }
        }
        __syncthreads();
    }

    float b1v[8], g1v[8], be1v[8];
    #pragma unroll
    for (int nt = 0; nt < 8; ++nt) {
        int c = l15 + nt * 16;
        b1v[nt] = b1[c]; g1v[nt] = g1[c]; be1v[nt] = be1[c];
    }
    {
        float s[4] = {0.f, 0.f, 0.f, 0.f}, s2[4] = {0.f, 0.f, 0.f, 0.f};
        #pragma unroll
        for (int nt = 0; nt < 8; ++nt)
            #pragma unroll
            for (int r = 0; r < 4; ++r) {
                float v = acc[nt][r] + b1v[nt];
                acc[nt][r] = v;
                s[r] += v; s2[r] += v * v;
            }
        #pragma unroll
        for (int r = 0; r < 4; ++r) {
            #pragma unroll
            for (int d = 1; d < 16; d <<= 1) {
                s[r]  += __shfl_xor(s[r],  d);
                s2[r] += __shfl_xor(s2[r], d);
            }
            float mu  = s[r] * (1.f / 128.f);
            float var = s2[r] * (1.f / 128.f) - mu * mu;
            float inv = rsqrtf(var + 1e-5f);
            int row = wv * 16 + g * 4 + r;
            #pragma unroll
            for (int nt = 0; nt < 8; ++nt) {
                float h = fmaxf((acc[nt][r] - mu) * inv * g1v[nt] + be1v[nt], 0.f);
                unsigned short hh, hl;
                split_bf(h, hh, hl);
                int k = l15 + nt * 16;
                int byte = row * 256 + ((k * 2) ^ ((row & 7) << 4));
                *reinterpret_cast<unsigned short*>(smem + YS_HI + byte) = hh;
                *reinterpret_cast<unsigned short*>(smem + YS_LO + byte) = hl;
            }
        }
    }

    auto stageW2 = [&](int kc2) {
        const char* src = w2img + (size_t)kc2 * 16384;
        #pragma unroll
        for (int i = 0; i < 4; ++i) {
            int b = (t + i * 256) * 16;
            *reinterpret_cast<uint4*>(smem + W2S + b) =
                *reinterpret_cast<const uint4*>(src + b);
        }
    };
    stageW2(0);
    __syncthreads();

    f32x4 acc2[4];
    #pragma unroll
    for (int nt = 0; nt < 4; ++nt)
        #pragma unroll
        for (int r = 0; r < 4; ++r) acc2[nt][r] = 0.f;

    for (int kc2 = 0; kc2 < 2; ++kc2) {
        if (kc2) { __syncthreads(); stageW2(1); __syncthreads(); }
        #pragma unroll
        for (int ks2 = 0; ks2 < 2; ++ks2) {
            int posY = (kc2 * 2 + ks2) * 64 + g * 16;
            int posW = ks2 * 64 + g * 16;
            short8v a_hi = ld_frag(smem + YS_HI, wv * 16 + l15, 256, posY);
            short8v a_lo = ld_frag(smem + YS_LO, wv * 16 + l15, 256, posY);
            #pragma unroll
            for (int nt = 0; nt < 4; ++nt) {
                short8v b_hi = ld_frag(smem + W2S,        nt * 16 + l15, 128, posW);
                short8v b_lo = ld_frag(smem + W2S + 8192, nt * 16 + l15, 128, posW);
                acc2[nt] = __builtin_amdgcn_mfma_f32_16x16x32_bf16(a_hi, b_hi, acc2[nt], 0, 0, 0);
                acc2[nt] = __builtin_amdgcn_mfma_f32_16x16x32_bf16(a_hi, b_lo, acc2[nt], 0, 0, 0);
                acc2[nt] = __builtin_amdgcn_mfma_f32_16x16x32_bf16(a_lo, b_hi, acc2[nt], 0, 0, 0);
            }
        }
    }

    float b2v[4], g2v[4], be2v[4];
    #pragma unroll
    for (int nt = 0; nt < 4; ++nt) {
        int c = l15 + nt * 16;
        b2v[nt] = b2[c]; g2v[nt] = g2[c]; be2v[nt] = be2[c];
    }
    #pragma unroll
    for (int r = 0; r < 4; ++r) {
        float vv[4];
        float ss = 0.f, ss2 = 0.f;
        #pragma unroll
        for (int nt = 0; nt < 4; ++nt) {
            float v = acc2[nt][r] + b2v[nt];
            vv[nt] = v; ss += v; ss2 += v * v;
        }
        #pragma unroll
        for (int d = 1; d < 16; d <<= 1) {
            ss  += __shfl_xor(ss,  d);
            ss2 += __shfl_xor(ss2, d);
        }
        float mu  = ss * (1.f / 64.f);
        float var = ss2 * (1.f / 64.f) - mu * mu;
        float inv = rsqrtf(var + 1e-5f);
        int node = r0 + wv * 16 + g * 4 + r;
        if (node < N) {
            #pragma unroll
            for (int nt = 0; nt < 4; ++nt)
                out[(size_t)node * DIM_O + l15 + nt * 16] = (vv[nt] - mu) * inv * g2v[nt] + be2v[nt];
        }
    }
}

__global__ __launch_bounds__(256, 3) void gnn_mlp_both(
    const float* __restrict__ p_emb,
    const unsigned short* __restrict__ p_emb16,
    const unsigned short* __restrict__ p_lo16,
    const char* __restrict__ msg_hi_p, const char* __restrict__ msg_lo_p,
    const float* __restrict__ c_emb,
    const unsigned short* __restrict__ c_emb16,
    const unsigned short* __restrict__ c_lo16,
    const char* __restrict__ msg_hi_c, const char* __restrict__ msg_lo_c,
    const char* __restrict__ w1p_img, const char* __restrict__ w2p_img,
    const char* __restrict__ w1c_img, const char* __restrict__ w2c_img,
    const float* __restrict__ p_b1, const float* __restrict__ p_g1,
    const float* __restrict__ p_be1,
    const float* __restrict__ p_b2, const float* __restrict__ p_g2,
    const float* __restrict__ p_be2,
    const float* __restrict__ c_b1, const float* __restrict__ c_g1,
    const float* __restrict__ c_be1,
    const float* __restrict__ c_b2, const float* __restrict__ c_g2,
    const float* __restrict__ c_be2,
    float* __restrict__ out, int NP, int NC, int NPB)
{
    if ((int)blockIdx.x < NPB) {
        mlp_body(blockIdx.x, p_emb, p_emb16, p_lo16, msg_hi_p, msg_lo_p,
                 w1p_img, w2p_img,
                 p_b1, p_g1, p_be1, p_b2, p_g2, p_be2, out, NP);
    } else {
        mlp_body(blockIdx.x - NPB, c_emb, c_emb16, c_lo16, msg_hi_c, msg_lo_c,
                 w1c_img, w2c_img,
                 c_b1, c_g1, c_be1, c_b2, c_g2, c_be2,
                 out + (size_t)NP * DIM_O, NC);
    }
}

extern "C" void kernel_launch(void* const* d_in, const int* in_sizes, int n_in,
                              void* d_out, int out_size, void* d_ws, size_t ws_size,
                              hipStream_t stream)
{
    const int*   pc_edges = (const int*)d_in[0];   // provider->code (2,E)
    const int*   cp_edges = (const int*)d_in[1];   // code->provider (2,E)
    const float* ew       = (const float*)d_in[2];
    const float* p_emb    = (const float*)d_in[3];
    const float* c_emb    = (const float*)d_in[4];
    const float* p_W1  = (const float*)d_in[5];
    const float* p_b1  = (const float*)d_in[6];
    const float* p_g1  = (const float*)d_in[7];
    const float* p_be1 = (const float*)d_in[8];
    const float* p_W2  = (const float*)d_in[9];
    const float* p_b2  = (const float*)d_in[10];
    const float* p_g2  = (const float*)d_in[11];
    const float* p_be2 = (const float*)d_in[12];
    const float* c_W1  = (const float*)d_in[13];
    const float* c_b1  = (const float*)d_in[14];
    const float* c_g1  = (const float*)d_in[15];
    const float* c_be1 = (const float*)d_in[16];
    const float* c_W2  = (const float*)d_in[17];
    const float* c_b2  = (const float*)d_in[18];
    const float* c_g2  = (const float*)d_in[19];
    const float* c_be2 = (const float*)d_in[20];

    const int E  = in_sizes[2];
    const int NP = in_sizes[3] / DIM_D;
    const int NC = in_sizes[4] / DIM_D;

    // workspace layout (msg planes first, contiguous: bins alias them)
    char* ws = (char*)d_ws;
    size_t off = 0;
    char* msg_hi_p = ws + off; off += (size_t)NP * 256;
    char* msg_lo_p = ws + off; off += (size_t)NP * 256;
    char* msg_hi_c = ws + off; off += (size_t)NC * 256;
    char* msg_lo_c = ws + off; off += (size_t)NC * 256;
    EdgeSW* csr_cp   = (EdgeSW*)(ws + off); off += (size_t)E * sizeof(EdgeSW);
    EdgeSW* csr_pc   = (EdgeSW*)(ws + off); off += (size_t)E * sizeof(EdgeSW);
    unsigned short* p_emb16 = (unsigned short*)(ws + off); off += (size_t)NP * DIM_D * 2;
    unsigned short* c_emb16 = (unsigned short*)(ws + off); off += (size_t)NC * DIM_D * 2;
    char* w1p_img = ws + off; off += 131072;   // 4 chunks x 32 KB
    char* w1c_img = ws + off; off += 131072;
    char* w2p_img = ws + off; off += 32768;    // 2 chunks x 16 KB
    char* w2c_img = ws + off; off += 32768;
    int* starts_p = (int*)(ws + off); off += (size_t)(NP + 4) * sizeof(int);
    int* starts_c = (int*)(ws + off); off += (size_t)(NC + 4) * sizeof(int);
    int* bcnt_p   = (int*)(ws + off); off += 1024 * sizeof(int);
    int* bcnt_c   = (int*)(ws + off); off += 1024 * sizeof(int);
    int* bstart_p = (int*)(ws + off); off += 1028 * sizeof(int);
    int* bstart_c = (int*)(ws + off); off += 1028 * sizeof(int);
    int* bcur_p   = (int*)(ws + off); off += 1024 * sizeof(int);
    int* bcur_c   = (int*)(ws + off); off += 1024 * sizeof(int);
    // optional pre-split emb lo tables (appended last; gated on ws_size)
    unsigned short* p_lo16 = (unsigned short*)(ws + off); off += (size_t)NP * DIM_D * 2;
    unsigned short* c_lo16 = (unsigned short*)(ws + off); off += (size_t)NC * DIM_D * 2;
    const bool use_lo = (off <= ws_size);
    if (!use_lo) { p_lo16 = nullptr; c_lo16 = nullptr; }

    // bin arrays alias the msg-plane space (dead until gather writes msg)
    uint2* bin_cp = (uint2*)msg_hi_p;
    uint2* bin_pc = bin_cp + E;

    const int NPB = (NP + 63) / 64;
    const int NCB = (NC + 63) / 64;
    const int np8 = NP * (DIM_D / 8);
    const int nc8 = NC * (DIM_D / 8);
    const int NBKp = (NP + BK_SIZE - 1) >> BK_SHIFT;
    const int NBKc = (NC + BK_SIZE - 1) >> BK_SHIFT;
    const int CB   = (E + CHUNK - 1) / CHUNK;

    hipMemsetAsync(bcnt_p, 0, 2048 * sizeof(int), stream);

    prep_hist_k<<<2 * CB + (40960 + np8 + nc8 + 255) / 256, 256, 0, stream>>>(
        cp_edges + E, bcnt_p, pc_edges + E, bcnt_c, E, CB, NBKp, NBKc,
        p_W1, p_W2, c_W1, c_W2, w1p_img, w2p_img, w1c_img, w2c_img,
        p_emb, c_emb, p_emb16, c_emb16, p_lo16, c_lo16, np8, nc8);

    scan_buckets<<<2, 256, 0, stream>>>(bcnt_p, bstart_p, bcur_p, NBKp,
                                        bcnt_c, bstart_c, bcur_c, NBKc);

    bin_both<<<2 * CB, 256, 0, stream>>>(cp_edges, bcur_p, bin_cp,
                                         pc_edges, bcur_c, bin_pc,
                                         ew, E, CB, NBKp, NBKc);

    place2_both<<<NBKp + NBKc, 256, 0, stream>>>(
        bin_cp, bstart_p, starts_p, csr_cp, NP, NBKp,
        bin_pc, bstart_c, starts_c, csr_pc, NC);

    gather_both<<<(NP + NC + 3) / 4, 256, 0, stream>>>(
        csr_cp, starts_p, c_emb16, msg_hi_p, msg_lo_p, NP,
        csr_pc, starts_c, p_emb16, msg_hi_c, msg_lo_c, NC);

    gnn_mlp_both<<<NPB + NCB, 256, 0, stream>>>(
        p_emb, p_emb16, p_lo16, msg_hi_p, msg_lo_p,
        c_emb, c_emb16, c_lo16, msg_hi_c, msg_lo_c,
        w1p_img, w2p_img, w1c_img, w2c_img,
        p_b1, p_g1, p_be1, p_b2, p_g2, p_be2,
        c_b1, c_g1, c_be1, c_b2, c_g2, c_be2,
        (float*)d_out, NP, NC, NPB);
}

// Round 13
// 301.099 us; speedup vs baseline: 1.0351x; 1.0351x over previous
//
#include <hip/hip_runtime.h>

#define DIM_D 128
#define DIM_2D 256
#define DIM_H 128
#define DIM_O 64

#define BK_SHIFT 7
#define BK_SIZE  128
#define CHUNK    8192

struct EdgeSW { int s; float w; };   // 8B packed

typedef __attribute__((ext_vector_type(8))) short short8v;  // 8 bf16 (4 VGPRs)
typedef __attribute__((ext_vector_type(4))) float f32x4;    // 4 fp32 acc
typedef __attribute__((ext_vector_type(2))) float f32x2;    // packed pair (v_pk_fma_f32)

__device__ __forceinline__ EdgeSW ld_edge_nt(const EdgeSW* p)
{
    unsigned long long v =
        __builtin_nontemporal_load(reinterpret_cast<const unsigned long long*>(p));
    EdgeSW e;
    e.s = (int)(unsigned)(v & 0xFFFFFFFFull);
    union { unsigned u; float f; } w; w.u = (unsigned)(v >> 32); e.w = w.f;
    return e;
}

__device__ __forceinline__ unsigned short f2bf_rne(float f)
{
    union { float f; unsigned u; } v; v.f = f;
    unsigned u = v.u + 0x7FFFu + ((v.u >> 16) & 1u);
    return (unsigned short)(u >> 16);
}

__device__ __forceinline__ float bf2f(unsigned short h)
{
    union { unsigned u; float f; } v; v.u = ((unsigned)h) << 16;
    return v.f;
}

// ---------------------------------------------------------------------------
// prep (weight images + emb bf16 tables) fused with bucket-level histogram.
// ---------------------------------------------------------------------------
__device__ __forceinline__ void split_bf(float x, unsigned short& hi, unsigned short& lo)
{
    union { float f; unsigned u; } v; v.f = x;
    hi = (unsigned short)(v.u >> 16);
    union { unsigned u; float f; } hv; hv.u = v.u & 0xFFFF0000u;
    union { float f; unsigned u; } rv; rv.f = x - hv.f;
    lo = (unsigned short)(rv.u >> 16);
}

__global__ __launch_bounds__(256) void prep_hist_k(
    const int* __restrict__ cp_dst, int* __restrict__ bcnt_p,
    const int* __restrict__ pc_dst, int* __restrict__ bcnt_c,
    int E, int CB, int nbk_p, int nbk_c,
    const float* __restrict__ W1p, const float* __restrict__ W2p,
    const float* __restrict__ W1c, const float* __restrict__ W2c,
    char* __restrict__ w1p_img, char* __restrict__ w2p_img,
    char* __restrict__ w1c_img, char* __restrict__ w2c_img,
    const float* __restrict__ pe, const float* __restrict__ ce,
    unsigned short* __restrict__ pe16, unsigned short* __restrict__ ce16,
    int np8, int nc8)
{
    __shared__ int lh[1024];
    int blk = blockIdx.x;
    const int t = threadIdx.x;

    if (blk < 2 * CB) {
        int b = blk;
        const int* dst; int* bcnt; int nbk;
        if (b < CB) { dst = cp_dst; bcnt = bcnt_p; nbk = nbk_p; }
        else        { dst = pc_dst; bcnt = bcnt_c; nbk = nbk_c; b -= CB; }
        const int e0 = b * CHUNK;
        const int e1 = min(e0 + CHUNK, E);
        if (e0 >= E) return;
        for (int i = t; i < nbk; i += 256) lh[i] = 0;
        __syncthreads();
        for (int i = e0 + t; i < e1; i += 256)
            atomicAdd(&lh[dst[i] >> BK_SHIFT], 1);
        __syncthreads();
        for (int i = t; i < nbk; i += 256) {
            int c = lh[i];
            if (c > 0) atomicAdd(&bcnt[i], c);
        }
        return;
    }

    int n = (blk - 2 * CB) * 256 + t;
    if (n < 40960) {
        int p = n;
        const float* W; char* img; int isW1; int lp;
        if (p < 16384)      { W = W1p; img = w1p_img; isW1 = 1; lp = p; }
        else if (p < 32768) { W = W1c; img = w1c_img; isW1 = 1; lp = p - 16384; }
        else if (p < 36864) { W = W2p; img = w2p_img; isW1 = 0; lp = p - 32768; }
        else                { W = W2c; img = w2c_img; isW1 = 0; lp = p - 36864; }
        int row, q, ncols;
        if (isW1) { row = lp >> 7; q = lp & 127; ncols = 256; }
        else      { row = lp >> 6; q = lp & 63;  ncols = 128; }
        int kc  = q >> 5;
        int cin = (q & 31) * 2;
        float a = W[(size_t)row * ncols + 2 * q];
        float b = W[(size_t)row * ncols + 2 * q + 1];
        unsigned short ah, al, bh, bl;
        split_bf(a, ah, al); split_bf(b, bh, bl);
        int half_sz = isW1 ? 16384 : 8192;
        size_t off = (size_t)kc * 2 * half_sz + (size_t)row * 128
                   + ((2 * cin) ^ ((row & 7) << 4));
        *reinterpret_cast<unsigned*>(img + off)           = (unsigned)ah | ((unsigned)bh << 16);
        *reinterpret_cast<unsigned*>(img + off + half_sz) = (unsigned)al | ((unsigned)bl << 16);
        return;
    }
    int i = n - 40960;
    const float* src; unsigned short* dst; int g;
    if (i < np8)            { src = pe; dst = pe16; g = i; }
    else if (i < np8 + nc8) { src = ce; dst = ce16; g = i - np8; }
    else return;
    float4 a = *reinterpret_cast<const float4*>(src + (size_t)g * 8);
    float4 b = *reinterpret_cast<const float4*>(src + (size_t)g * 8 + 4);
    uint4 o;
    o.x = (unsigned)f2bf_rne(a.x) | ((unsigned)f2bf_rne(a.y) << 16);
    o.y = (unsigned)f2bf_rne(a.z) | ((unsigned)f2bf_rne(a.w) << 16);
    o.z = (unsigned)f2bf_rne(b.x) | ((unsigned)f2bf_rne(b.y) << 16);
    o.w = (unsigned)f2bf_rne(b.z) | ((unsigned)f2bf_rne(b.w) << 16);
    *reinterpret_cast<uint4*>(dst + (size_t)g * 8) = o;
}

// ---------------------------------------------------------------------------
// Exclusive prefix over bucket counts; seeds bstart (with sentinel) and bcur.
// ---------------------------------------------------------------------------
__global__ __launch_bounds__(256) void scan_buckets(
    const int* __restrict__ bcnt_p, int* __restrict__ bstart_p,
    int* __restrict__ bcur_p, int nbk_p,
    const int* __restrict__ bcnt_c, int* __restrict__ bstart_c,
    int* __restrict__ bcur_c, int nbk_c)
{
    const int* bcnt; int* bstart; int* bcur; int nbk;
    if (blockIdx.x == 0) { bcnt = bcnt_p; bstart = bstart_p; bcur = bcur_p; nbk = nbk_p; }
    else                 { bcnt = bcnt_c; bstart = bstart_c; bcur = bcur_c; nbk = nbk_c; }
    int t = threadIdx.x;
    int base = t * 4;
    int v[4]; int s = 0;
    #pragma unroll
    for (int k = 0; k < 4; ++k) { int i = base + k; v[k] = (i < nbk) ? bcnt[i] : 0; s += v[k]; }
    __shared__ int sh[256];
    sh[t] = s; __syncthreads();
    for (int off = 1; off < 256; off <<= 1) {
        int x = 0;
        if (t >= off) x = sh[t - off];
        __syncthreads();
        if (t >= off) sh[t] += x;
        __syncthreads();
    }
    int run = (t > 0 ? sh[t - 1] : 0);
    #pragma unroll
    for (int k = 0; k < 4; ++k) {
        int i = base + k;
        if (i < nbk) {
            bstart[i] = run;
            bcur[i]   = run;
            run += v[k];
            if (i == nbk - 1) bstart[nbk] = run;
        }
    }
}

// ---------------------------------------------------------------------------
// Pass A: bin edges by dst>>7 with block-aggregated cursor updates.
// ---------------------------------------------------------------------------
__global__ __launch_bounds__(256) void bin_both(
    const int* __restrict__ cp_edges, int* __restrict__ bcur_p,
    uint2* __restrict__ bin_cp,
    const int* __restrict__ pc_edges, int* __restrict__ bcur_c,
    uint2* __restrict__ bin_pc,
    const float* __restrict__ ew, int E, int CB, int NBKp, int NBKc)
{
    __shared__ int lh[1024];
    int b = blockIdx.x;
    const int* src; const int* dst; int* bcur; uint2* bin; int nbk;
    if (b < CB) { src = cp_edges; dst = cp_edges + E; bcur = bcur_p; bin = bin_cp; nbk = NBKp; }
    else        { src = pc_edges; dst = pc_edges + E; bcur = bcur_c; bin = bin_pc; nbk = NBKc; b -= CB; }
    const int t  = threadIdx.x;
    const int e0 = b * CHUNK;
    const int e1 = min(e0 + CHUNK, E);
    if (e0 >= E) return;

    for (int i = t; i < nbk; i += 256) lh[i] = 0;
    __syncthreads();
    for (int i = e0 + t; i < e1; i += 256)
        atomicAdd(&lh[dst[i] >> BK_SHIFT], 1);
    __syncthreads();

    for (int i = t; i < nbk; i += 256) {
        int c = lh[i];
        if (c > 0) lh[i] = atomicAdd(&bcur[i], c);
    }
    __syncthreads();

    for (int i = e0 + t; i < e1; i += 256) {
        int d = dst[i];
        int pos = atomicAdd(&lh[d >> BK_SHIFT], 1);
        uint2 r;
        r.x = (unsigned)src[i] | ((unsigned)(d & (BK_SIZE - 1)) << 25);
        union { float f; unsigned u; } w; w.f = ew[i];
        r.y = w.u;
        bin[pos] = r;
    }
}

// ---------------------------------------------------------------------------
// Pass B: one block per bucket; local per-node starts; L2-local scatter.
// ---------------------------------------------------------------------------
__global__ __launch_bounds__(256) void place2_both(
    const uint2* __restrict__ bin_cp, const int* __restrict__ bstart_p,
    int* __restrict__ starts_p, EdgeSW* __restrict__ csr_cp, int NP, int NBKp,
    const uint2* __restrict__ bin_pc, const int* __restrict__ bstart_c,
    int* __restrict__ starts_c, EdgeSW* __restrict__ csr_pc, int NC)
{
    int b = blockIdx.x;
    const uint2* bin; const int* bstart; int* starts; EdgeSW* csr; int N;
    if (b < NBKp) { bin = bin_cp; bstart = bstart_p; starts = starts_p; csr = csr_cp; N = NP; }
    else          { bin = bin_pc; bstart = bstart_c; starts = starts_c; csr = csr_pc; N = NC; b -= NBKp; }
    int d0 = b << BK_SHIFT;
    if (d0 >= N) return;
    int nd = min(BK_SIZE, N - d0);

    __shared__ int lcnt[BK_SIZE];
    __shared__ int lpre[BK_SIZE];
    __shared__ int lcur[BK_SIZE];
    int t = threadIdx.x;
    if (t < BK_SIZE) lcnt[t] = 0;
    __syncthreads();

    int rs = bstart[b], re = bstart[b + 1];
    for (int i = rs + t; i < re; i += 256)
        atomicAdd(&lcnt[bin[i].x >> 25], 1);
    __syncthreads();

    if (t < BK_SIZE) lpre[t] = lcnt[t];
    __syncthreads();
    #pragma unroll
    for (int off = 1; off < BK_SIZE; off <<= 1) {
        int x = 0;
        if (t < BK_SIZE && t >= off) x = lpre[t - off];
        __syncthreads();
        if (t < BK_SIZE && t >= off) lpre[t] += x;
        __syncthreads();
    }
    if (t < BK_SIZE) {
        int excl = rs + lpre[t] - lcnt[t];
        lcur[t] = excl;
        if (t < nd) starts[d0 + t] = excl;
    }
    if (t == 0 && d0 + BK_SIZE >= N) starts[N] = re;
    __syncthreads();

    for (int i = rs + t; i < re; i += 256) {
        uint2 r = bin[i];
        int dlo = (int)(r.x >> 25);
        int pos = atomicAdd(&lcur[dlo], 1);
        EdgeSW e;
        e.s = (int)(r.x & 0x1FFFFFFu);
        union { unsigned u; float f; } w; w.u = r.y; e.w = w.f;
        csr[pos] = e;
    }
}

// ---------------------------------------------------------------------------
// Gather: wave per node; 16 lanes/row (uint4 = 8 bf16), 4 edges across wave
// quarters. Packed f32x2 accumulate; 32-bit indexed emb loads. Output:
// swizzled bf16 hi/lo msg planes (the MLP's XS image).
// ---------------------------------------------------------------------------
__device__ __forceinline__ void fma8p(f32x2* acc, uint4 v, float w)
{
    union { unsigned u; float f; } a, b;
    f32x2 p;
    a.u = v.x << 16; b.u = v.x & 0xFFFF0000u; p[0] = a.f; p[1] = b.f; acc[0] += p * w;
    a.u = v.y << 16; b.u = v.y & 0xFFFF0000u; p[0] = a.f; p[1] = b.f; acc[1] += p * w;
    a.u = v.z << 16; b.u = v.z & 0xFFFF0000u; p[0] = a.f; p[1] = b.f; acc[2] += p * w;
    a.u = v.w << 16; b.u = v.w & 0xFFFF0000u; p[0] = a.f; p[1] = b.f; acc[3] += p * w;
}

__global__ __launch_bounds__(256) void gather_both(
    const EdgeSW* __restrict__ csr_cp, const int* __restrict__ starts_p,
    const unsigned short* __restrict__ c_emb16,
    char* __restrict__ msg_hi_p, char* __restrict__ msg_lo_p, int NP,
    const EdgeSW* __restrict__ csr_pc, const int* __restrict__ starts_c,
    const unsigned short* __restrict__ p_emb16,
    char* __restrict__ msg_hi_c, char* __restrict__ msg_lo_c, int NC)
{
    int wv = (blockIdx.x * 256 + threadIdx.x) >> 6;
    int lane = threadIdx.x & 63;
    const EdgeSW* csr; const int* starts; const unsigned short* emb;
    char* mh; char* ml; int n;
    if (wv < NP)           { csr = csr_cp; starts = starts_p; emb = c_emb16;
                             mh = msg_hi_p; ml = msg_lo_p; n = wv; }
    else if (wv < NP + NC) { csr = csr_pc; starts = starts_c; emb = p_emb16;
                             mh = msg_hi_c; ml = msg_lo_c; n = wv - NP; }
    else return;

    const int sub = lane >> 4;          // edge slot within quad
    const int l15 = lane & 15;
    const int cb  = l15 * 8;            // col base (8 bf16 = 16B)
    const uint4* embq = reinterpret_cast<const uint4*>(emb);

    auto eidx = [&](int s) -> unsigned {
        return ((((unsigned)s) & 0xFFFFFFu) << 4) | (unsigned)l15;
    };

    int s0 = starts[n], s1 = starts[n + 1];
    f32x2 a2[4];
    a2[0] = 0.f; a2[1] = 0.f; a2[2] = 0.f; a2[3] = 0.f;
    float degw = 0.f;
    int i = s0;
    for (; i + 16 <= s1; i += 16) {
        EdgeSW e0 = ld_edge_nt(csr + i + sub);
        EdgeSW e1 = ld_edge_nt(csr + i + 4 + sub);
        EdgeSW e2 = ld_edge_nt(csr + i + 8 + sub);
        EdgeSW e3 = ld_edge_nt(csr + i + 12 + sub);
        uint4 v0 = embq[eidx(e0.s)];
        uint4 v1 = embq[eidx(e1.s)];
        uint4 v2 = embq[eidx(e2.s)];
        uint4 v3 = embq[eidx(e3.s)];
        fma8p(a2, v0, e0.w); fma8p(a2, v1, e1.w);
        fma8p(a2, v2, e2.w); fma8p(a2, v3, e3.w);
        degw += e0.w + e1.w + e2.w + e3.w;
    }
    if (i + 8 <= s1) {
        EdgeSW e0 = ld_edge_nt(csr + i + sub);
        EdgeSW e1 = ld_edge_nt(csr + i + 4 + sub);
        uint4 v0 = embq[eidx(e0.s)];
        uint4 v1 = embq[eidx(e1.s)];
        fma8p(a2, v0, e0.w); fma8p(a2, v1, e1.w);
        degw += e0.w + e1.w;
        i += 8;
    }
    for (; i < s1; i += 4) {
        int idx = i + sub;
        if (idx < s1) {
            EdgeSW e0 = ld_edge_nt(csr + idx);
            uint4 v0 = embq[eidx(e0.s)];
            fma8p(a2, v0, e0.w);
            degw += e0.w;
        }
    }
    degw += __shfl_xor(degw, 16);
    degw += __shfl_xor(degw, 32);
    #pragma unroll
    for (int j = 0; j < 4; ++j) {
        a2[j][0] += __shfl_xor(a2[j][0], 16);
        a2[j][0] += __shfl_xor(a2[j][0], 32);
        a2[j][1] += __shfl_xor(a2[j][1], 16);
        a2[j][1] += __shfl_xor(a2[j][1], 32);
    }
    if (lane < 16) {
        float inv = 1.0f / (degw + 1e-8f);
        unsigned h[8], l[8];
        #pragma unroll
        for (int j = 0; j < 8; ++j) {
            float x = a2[j >> 1][j & 1] * inv;
            unsigned short hh = f2bf_rne(x);
            unsigned short ll = f2bf_rne(x - bf2f(hh));
            h[j] = hh; l[j] = ll;
        }
        uint4 hv, lv;
        hv.x = h[0] | (h[1] << 16); hv.y = h[2] | (h[3] << 16);
        hv.z = h[4] | (h[5] << 16); hv.w = h[6] | (h[7] << 16);
        lv.x = l[0] | (l[1] << 16); lv.y = l[2] | (l[3] << 16);
        lv.z = l[4] | (l[5] << 16); lv.w = l[6] | (l[7] << 16);
        size_t base = (size_t)n * 256 + ((cb * 2) ^ ((n & 7) << 4));
        *reinterpret_cast<uint4*>(mh + base) = hv;
        *reinterpret_cast<uint4*>(ml + base) = lv;
    }
}

// ---------------------------------------------------------------------------
// Fused MLP via bf16x3 MFMA, 128 nodes / 512 threads / 8 waves per block.
// Each wave owns a 16-row m-tile (identical per-wave math to the 64-node
// version); weight images amortized over 2x nodes, barriers/node halved.
// LDS (80 KB -> 2 blocks/CU = 16 waves/CU):
//   phase1: XS_HI 0 (16K) | XS_LO 16K | W1S hi 32K | W1S lo 48K   = 64K
//   phase2: YS_HI 0 (32K) | YS_LO 32K | W2S hi 64K | W2S lo 72K   = 80K
// ---------------------------------------------------------------------------
#define XS_HI  0
#define XS_LO  16384
#define W1S    32768     // hi 16K at W1S, lo 16K at W1S+16384
#define YS_HI  0
#define YS_LO  32768
#define W2S    65536     // hi 8K at W2S, lo 8K at W2S+8192
#define SMEM_BYTES 81920

__device__ __forceinline__ void stage_pair(char* hi_base, char* lo_base,
                                           int row, int rowbytes, int posB, float4 v)
{
    int byte = row * rowbytes + (posB ^ ((row & 7) << 4));
    unsigned short h0, h1, h2, h3, l0, l1, l2, l3;
    split_bf(v.x, h0, l0); split_bf(v.y, h1, l1);
    split_bf(v.z, h2, l2); split_bf(v.w, h3, l3);
    uint2 hp, lp;
    hp.x = (unsigned)h0 | ((unsigned)h1 << 16);
    hp.y = (unsigned)h2 | ((unsigned)h3 << 16);
    lp.x = (unsigned)l0 | ((unsigned)l1 << 16);
    lp.y = (unsigned)l2 | ((unsigned)l3 << 16);
    *reinterpret_cast<uint2*>(hi_base + byte) = hp;
    *reinterpret_cast<uint2*>(lo_base + byte) = lp;
}

__device__ __forceinline__ short8v ld_frag(const char* base, int row, int rowbytes, int posB)
{
    int byte = row * rowbytes + (posB ^ ((row & 7) << 4));
    return *reinterpret_cast<const short8v*>(base + byte);
}

__device__ __forceinline__ void mlp_body(int blk,
    const float* __restrict__ emb,
    const char* __restrict__ msg_hi, const char* __restrict__ msg_lo,
    const char* __restrict__ w1img, const char* __restrict__ w2img,
    const float* __restrict__ b1, const float* __restrict__ g1,
    const float* __restrict__ be1,
    const float* __restrict__ b2, const float* __restrict__ g2,
    const float* __restrict__ be2,
    float* __restrict__ out, int N)
{
    __shared__ uint4 smem4[SMEM_BYTES / 16];
    char* smem = reinterpret_cast<char*>(smem4);

    const int t    = threadIdx.x;       // 0..511
    const int lane = t & 63;
    const int wv   = t >> 6;            // wave 0..7, owns rows 16wv..16wv+15
    const int l15  = lane & 15;
    const int g    = lane >> 4;
    const int r0   = blk * 128;

    f32x4 acc[8];
    #pragma unroll
    for (int nt = 0; nt < 8; ++nt)
        #pragma unroll
        for (int r = 0; r < 4; ++r) acc[nt][r] = 0.f;

    for (int kc = 0; kc < 4; ++kc) {
        if (kc < 2) {
            // stage X chunk from fp32 emb (split): 128 rows x 64 cols
            #pragma unroll
            for (int i = 0; i < 4; ++i) {
                int lin = t + i * 512;
                int row = lin >> 4;            // 0..127
                int c4  = (lin & 15) << 2;
                int node = r0 + row;
                float4 v = make_float4(0.f, 0.f, 0.f, 0.f);
                if (node < N)
                    v = *reinterpret_cast<const float4*>(emb + (size_t)node * DIM_D + kc * 64 + c4);
                stage_pair(smem + XS_HI, smem + XS_LO, row, 128, c4 * 2, v);
            }
        } else {
            // stage msg chunk: pure copies from pre-swizzled planes
            int base = (kc - 2) * 128;
            #pragma unroll
            for (int q = 0; q < 2; ++q) {
                int idx = t + q * 512;
                int row = idx >> 3;            // 0..127
                int j   = idx & 7;
                int node = r0 + row;
                uint4 vh = make_uint4(0, 0, 0, 0), vl = make_uint4(0, 0, 0, 0);
                if (node < N) {
                    vh = *reinterpret_cast<const uint4*>(msg_hi + (size_t)node * 256 + base + j * 16);
                    vl = *reinterpret_cast<const uint4*>(msg_lo + (size_t)node * 256 + base + j * 16);
                }
                *reinterpret_cast<uint4*>(smem + XS_HI + row * 128 + j * 16) = vh;
                *reinterpret_cast<uint4*>(smem + XS_LO + row * 128 + j * 16) = vl;
            }
        }
        // stage W1 chunk (hi 16K + lo 16K): 2048 uint4 / 512 threads
        {
            const char* src = w1img + (size_t)kc * 32768;
            #pragma unroll
            for (int i = 0; i < 4; ++i) {
                int b = (t + i * 512) * 16;
                *reinterpret_cast<uint4*>(smem + W1S + b) =
                    *reinterpret_cast<const uint4*>(src + b);
            }
        }
        __syncthreads();
        #pragma unroll
        for (int ks = 0; ks < 2; ++ks) {
            int pos = ks * 64 + g * 16;
            short8v a_hi = ld_frag(smem + XS_HI, wv * 16 + l15, 128, pos);
            short8v a_lo = ld_frag(smem + XS_LO, wv * 16 + l15, 128, pos);
            #pragma unroll
            for (int nt = 0; nt < 8; ++nt) {
                short8v b_hi = ld_frag(smem + W1S,         nt * 16 + l15, 128, pos);
                short8v b_lo = ld_frag(smem + W1S + 16384, nt * 16 + l15, 128, pos);
                acc[nt] = __builtin_amdgcn_mfma_f32_16x16x32_bf16(a_hi, b_hi, acc[nt], 0, 0, 0);
                acc[nt] = __builtin_amdgcn_mfma_f32_16x16x32_bf16(a_hi, b_lo, acc[nt], 0, 0, 0);
                acc[nt] = __builtin_amdgcn_mfma_f32_16x16x32_bf16(a_lo, b_hi, acc[nt], 0, 0, 0);
            }
        }
        __syncthreads();
    }

    // ---------------- LN1 + relu (wave-local), write Y to LDS as bf16 pair --
    float b1v[8], g1v[8], be1v[8];
    #pragma unroll
    for (int nt = 0; nt < 8; ++nt) {
        int c = l15 + nt * 16;
        b1v[nt] = b1[c]; g1v[nt] = g1[c]; be1v[nt] = be1[c];
    }
    {
        float s[4] = {0.f, 0.f, 0.f, 0.f}, s2[4] = {0.f, 0.f, 0.f, 0.f};
        #pragma unroll
        for (int nt = 0; nt < 8; ++nt)
            #pragma unroll
            for (int r = 0; r < 4; ++r) {
                float v = acc[nt][r] + b1v[nt];
                acc[nt][r] = v;
                s[r] += v; s2[r] += v * v;
            }
        #pragma unroll
        for (int r = 0; r < 4; ++r) {
            #pragma unroll
            for (int d = 1; d < 16; d <<= 1) {
                s[r]  += __shfl_xor(s[r],  d);
                s2[r] += __shfl_xor(s2[r], d);
            }
            float mu  = s[r] * (1.f / 128.f);
            float var = s2[r] * (1.f / 128.f) - mu * mu;
            float inv = rsqrtf(var + 1e-5f);
            int row = wv * 16 + g * 4 + r;     // 0..127
            #pragma unroll
            for (int nt = 0; nt < 8; ++nt) {
                float h = fmaxf((acc[nt][r] - mu) * inv * g1v[nt] + be1v[nt], 0.f);
                unsigned short hh, hl;
                split_bf(h, hh, hl);
                int k = l15 + nt * 16;
                int byte = row * 256 + ((k * 2) ^ ((row & 7) << 4));
                *reinterpret_cast<unsigned short*>(smem + YS_HI + byte) = hh;
                *reinterpret_cast<unsigned short*>(smem + YS_LO + byte) = hl;
            }
        }
    }

    // ---------------- GEMM2 ----------------
    auto stageW2 = [&](int kc2) {
        const char* src = w2img + (size_t)kc2 * 16384;
        #pragma unroll
        for (int i = 0; i < 2; ++i) {
            int b = (t + i * 512) * 16;
            *reinterpret_cast<uint4*>(smem + W2S + b) =
                *reinterpret_cast<const uint4*>(src + b);
        }
    };
    stageW2(0);
    __syncthreads();

    f32x4 acc2[4];
    #pragma unroll
    for (int nt = 0; nt < 4; ++nt)
        #pragma unroll
        for (int r = 0; r < 4; ++r) acc2[nt][r] = 0.f;

    for (int kc2 = 0; kc2 < 2; ++kc2) {
        if (kc2) { __syncthreads(); stageW2(1); __syncthreads(); }
        #pragma unroll
        for (int ks2 = 0; ks2 < 2; ++ks2) {
            int posY = (kc2 * 2 + ks2) * 64 + g * 16;
            int posW = ks2 * 64 + g * 16;
            short8v a_hi = ld_frag(smem + YS_HI, wv * 16 + l15, 256, posY);
            short8v a_lo = ld_frag(smem + YS_LO, wv * 16 + l15, 256, posY);
            #pragma unroll
            for (int nt = 0; nt < 4; ++nt) {
                short8v b_hi = ld_frag(smem + W2S,        nt * 16 + l15, 128, posW);
                short8v b_lo = ld_frag(smem + W2S + 8192, nt * 16 + l15, 128, posW);
                acc2[nt] = __builtin_amdgcn_mfma_f32_16x16x32_bf16(a_hi, b_hi, acc2[nt], 0, 0, 0);
                acc2[nt] = __builtin_amdgcn_mfma_f32_16x16x32_bf16(a_hi, b_lo, acc2[nt], 0, 0, 0);
                acc2[nt] = __builtin_amdgcn_mfma_f32_16x16x32_bf16(a_lo, b_hi, acc2[nt], 0, 0, 0);
            }
        }
    }

    // ---------------- LN2 (wave-local) + store ----------------
    float b2v[4], g2v[4], be2v[4];
    #pragma unroll
    for (int nt = 0; nt < 4; ++nt) {
        int c = l15 + nt * 16;
        b2v[nt] = b2[c]; g2v[nt] = g2[c]; be2v[nt] = be2[c];
    }
    #pragma unroll
    for (int r = 0; r < 4; ++r) {
        float vv[4];
        float ss = 0.f, ss2 = 0.f;
        #pragma unroll
        for (int nt = 0; nt < 4; ++nt) {
            float v = acc2[nt][r] + b2v[nt];
            vv[nt] = v; ss += v; ss2 += v * v;
        }
        #pragma unroll
        for (int d = 1; d < 16; d <<= 1) {
            ss  += __shfl_xor(ss,  d);
            ss2 += __shfl_xor(ss2, d);
        }
        float mu  = ss * (1.f / 64.f);
        float var = ss2 * (1.f / 64.f) - mu * mu;
        float inv = rsqrtf(var + 1e-5f);
        int node = r0 + wv * 16 + g * 4 + r;
        if (node < N) {
            #pragma unroll
            for (int nt = 0; nt < 4; ++nt)
                out[(size_t)node * DIM_O + l15 + nt * 16] = (vv[nt] - mu) * inv * g2v[nt] + be2v[nt];
        }
    }
}

__global__ __launch_bounds__(512, 4) void gnn_mlp_both(
    const float* __restrict__ p_emb,
    const char* __restrict__ msg_hi_p, const char* __restrict__ msg_lo_p,
    const float* __restrict__ c_emb,
    const char* __restrict__ msg_hi_c, const char* __restrict__ msg_lo_c,
    const char* __restrict__ w1p_img, const char* __restrict__ w2p_img,
    const char* __restrict__ w1c_img, const char* __restrict__ w2c_img,
    const float* __restrict__ p_b1, const float* __restrict__ p_g1,
    const float* __restrict__ p_be1,
    const float* __restrict__ p_b2, const float* __restrict__ p_g2,
    const float* __restrict__ p_be2,
    const float* __restrict__ c_b1, const float* __restrict__ c_g1,
    const float* __restrict__ c_be1,
    const float* __restrict__ c_b2, const float* __restrict__ c_g2,
    const float* __restrict__ c_be2,
    float* __restrict__ out, int NP, int NC, int NPB)
{
    if ((int)blockIdx.x < NPB) {
        mlp_body(blockIdx.x, p_emb, msg_hi_p, msg_lo_p, w1p_img, w2p_img,
                 p_b1, p_g1, p_be1, p_b2, p_g2, p_be2, out, NP);
    } else {
        mlp_body(blockIdx.x - NPB, c_emb, msg_hi_c, msg_lo_c, w1c_img, w2c_img,
                 c_b1, c_g1, c_be1, c_b2, c_g2, c_be2,
                 out + (size_t)NP * DIM_O, NC);
    }
}

extern "C" void kernel_launch(void* const* d_in, const int* in_sizes, int n_in,
                              void* d_out, int out_size, void* d_ws, size_t ws_size,
                              hipStream_t stream)
{
    const int*   pc_edges = (const int*)d_in[0];   // provider->code (2,E)
    const int*   cp_edges = (const int*)d_in[1];   // code->provider (2,E)
    const float* ew       = (const float*)d_in[2];
    const float* p_emb    = (const float*)d_in[3];
    const float* c_emb    = (const float*)d_in[4];
    const float* p_W1  = (const float*)d_in[5];
    const float* p_b1  = (const float*)d_in[6];
    const float* p_g1  = (const float*)d_in[7];
    const float* p_be1 = (const float*)d_in[8];
    const float* p_W2  = (const float*)d_in[9];
    const float* p_b2  = (const float*)d_in[10];
    const float* p_g2  = (const float*)d_in[11];
    const float* p_be2 = (const float*)d_in[12];
    const float* c_W1  = (const float*)d_in[13];
    const float* c_b1  = (const float*)d_in[14];
    const float* c_g1  = (const float*)d_in[15];
    const float* c_be1 = (const float*)d_in[16];
    const float* c_W2  = (const float*)d_in[17];
    const float* c_b2  = (const float*)d_in[18];
    const float* c_g2  = (const float*)d_in[19];
    const float* c_be2 = (const float*)d_in[20];

    const int E  = in_sizes[2];
    const int NP = in_sizes[3] / DIM_D;
    const int NC = in_sizes[4] / DIM_D;

    // workspace layout (msg planes first, contiguous: bins alias them)
    char* ws = (char*)d_ws;
    size_t off = 0;
    char* msg_hi_p = ws + off; off += (size_t)NP * 256;
    char* msg_lo_p = ws + off; off += (size_t)NP * 256;
    char* msg_hi_c = ws + off; off += (size_t)NC * 256;
    char* msg_lo_c = ws + off; off += (size_t)NC * 256;
    EdgeSW* csr_cp   = (EdgeSW*)(ws + off); off += (size_t)E * sizeof(EdgeSW);
    EdgeSW* csr_pc   = (EdgeSW*)(ws + off); off += (size_t)E * sizeof(EdgeSW);
    unsigned short* p_emb16 = (unsigned short*)(ws + off); off += (size_t)NP * DIM_D * 2;
    unsigned short* c_emb16 = (unsigned short*)(ws + off); off += (size_t)NC * DIM_D * 2;
    char* w1p_img = ws + off; off += 131072;   // 4 chunks x 32 KB
    char* w1c_img = ws + off; off += 131072;
    char* w2p_img = ws + off; off += 32768;    // 2 chunks x 16 KB
    char* w2c_img = ws + off; off += 32768;
    int* starts_p = (int*)(ws + off); off += (size_t)(NP + 4) * sizeof(int);
    int* starts_c = (int*)(ws + off); off += (size_t)(NC + 4) * sizeof(int);
    int* bcnt_p   = (int*)(ws + off); off += 1024 * sizeof(int);
    int* bcnt_c   = (int*)(ws + off); off += 1024 * sizeof(int);
    int* bstart_p = (int*)(ws + off); off += 1028 * sizeof(int);
    int* bstart_c = (int*)(ws + off); off += 1028 * sizeof(int);
    int* bcur_p   = (int*)(ws + off); off += 1024 * sizeof(int);
    int* bcur_c   = (int*)(ws + off); off += 1024 * sizeof(int);
    (void)ws_size;

    // bin arrays alias the msg-plane space (dead until gather writes msg)
    uint2* bin_cp = (uint2*)msg_hi_p;
    uint2* bin_pc = bin_cp + E;

    const int NPB = (NP + 127) / 128;
    const int NCB = (NC + 127) / 128;
    const int np8 = NP * (DIM_D / 8);
    const int nc8 = NC * (DIM_D / 8);
    const int NBKp = (NP + BK_SIZE - 1) >> BK_SHIFT;
    const int NBKc = (NC + BK_SIZE - 1) >> BK_SHIFT;
    const int CB   = (E + CHUNK - 1) / CHUNK;

    hipMemsetAsync(bcnt_p, 0, 2048 * sizeof(int), stream);

    prep_hist_k<<<2 * CB + (40960 + np8 + nc8 + 255) / 256, 256, 0, stream>>>(
        cp_edges + E, bcnt_p, pc_edges + E, bcnt_c, E, CB, NBKp, NBKc,
        p_W1, p_W2, c_W1, c_W2, w1p_img, w2p_img, w1c_img, w2c_img,
        p_emb, c_emb, p_emb16, c_emb16, np8, nc8);

    scan_buckets<<<2, 256, 0, stream>>>(bcnt_p, bstart_p, bcur_p, NBKp,
                                        bcnt_c, bstart_c, bcur_c, NBKc);

    bin_both<<<2 * CB, 256, 0, stream>>>(cp_edges, bcur_p, bin_cp,
                                         pc_edges, bcur_c, bin_pc,
                                         ew, E, CB, NBKp, NBKc);

    place2_both<<<NBKp + NBKc, 256, 0, stream>>>(
        bin_cp, bstart_p, starts_p, csr_cp, NP, NBKp,
        bin_pc, bstart_c, starts_c, csr_pc, NC);

    gather_both<<<(NP + NC + 3) / 4, 256, 0, stream>>>(
        csr_cp, starts_p, c_emb16, msg_hi_p, msg_lo_p, NP,
        csr_pc, starts_c, p_emb16, msg_hi_c, msg_lo_c, NC);

    gnn_mlp_both<<<NPB + NCB, 512, 0, stream>>>(
        p_emb, msg_hi_p, msg_lo_p, c_emb, msg_hi_c, msg_lo_c,
        w1p_img, w2p_img, w1c_img, w2c_img,
        p_b1, p_g1, p_be1, p_b2, p_g2, p_be2,
        c_b1, c_g1, c_be1, c_b2, c_g2, c_be2,
        (float*)d_out, NP, NC, NPB);
}